// Round 1
// baseline (387.243 us; speedup 1.0000x reference)
//
#include <hip/hip_runtime.h>
#include <hip/hip_bf16.h>
#include <math.h>
#include <stdint.h>

#define NB 2
#define NS 2048
#define NH 16
#define NDH 128
#define NDR 64
#define NHID 2048
#define NC 512

typedef unsigned short u16;
typedef short short8 __attribute__((ext_vector_type(8)));
typedef short short4v __attribute__((ext_vector_type(4)));
typedef float f32x4 __attribute__((ext_vector_type(4)));

__device__ __forceinline__ u16 f2bf(float f) {
  union { float f; uint32_t u; } c; c.f = f;
  uint32_t u = c.u + 0x7fffu + ((c.u >> 16) & 1u);
  return (u16)(u >> 16);
}
__device__ __forceinline__ float bf2f(u16 b) {
  union { uint32_t u; float f; } c; c.u = ((uint32_t)b) << 16;
  return c.f;
}
__device__ __forceinline__ void async16(const void* g, void* l) {
  __builtin_amdgcn_global_load_lds((const __attribute__((address_space(1))) void*)g,
                                   (__attribute__((address_space(3))) void*)l, 16, 0, 0);
}

// ---------------- cast f32 -> bf16 ----------------
struct CastArgs {
  const float* src[8];
  u16* dst[8];
  int start[8];   // block prefix starts
};

__global__ __launch_bounds__(256) void cast_kernel(CastArgs a) {
  int blk = blockIdx.x;
  int ti = 0;
#pragma unroll
  for (int i = 1; i < 8; ++i) ti += (blk >= a.start[i]) ? 1 : 0;
  size_t off = (size_t)(blk - a.start[ti]) * 2048 + (size_t)threadIdx.x * 8;
  const float4* s = (const float4*)(a.src[ti] + off);
  float4 v0 = s[0], v1 = s[1];
  u16 o[8];
  o[0] = f2bf(v0.x); o[1] = f2bf(v0.y); o[2] = f2bf(v0.z); o[3] = f2bf(v0.w);
  o[4] = f2bf(v1.x); o[5] = f2bf(v1.y); o[6] = f2bf(v1.z); o[7] = f2bf(v1.w);
  *(short8*)(a.dst[ti] + off) = *(short8*)o;
}

// ---------------- generic B^T GEMM (bf16 MFMA, f32 acc) ----------------
// C[m,n] = sum_k A[m,k]*W[n,k] + bias[n]; A: M x K rowmajor, W: Nseg x K rowmajor.
struct GemmSeg {
  const u16* A;
  const u16* W;
  const float* bias;
  void* dst;
  int K;
  int mode;   // 0: bf16 rowmajor [M][ldc]; 1: V^T pack -> [b][h][dv][s]; 2: f32 rowmajor
  int ldc;
};
struct GemmArgs {
  GemmSeg seg[5];
  int nbstart[6];
  int nseg;
};

__global__ __launch_bounds__(256) void gemm_bt(GemmArgs ga) {
  __shared__ u16 la[128 * 32];
  __shared__ u16 lb[128 * 32];
  const int nb = blockIdx.x, mb = blockIdx.y;
  int si = 0;
  for (int i = 1; i < ga.nseg; ++i) si += (nb >= ga.nbstart[i]) ? 1 : 0;
  GemmSeg sg = ga.seg[si];
  const int nbl = nb - ga.nbstart[si];
  const int K = sg.K;
  const u16* Ap = sg.A + (size_t)mb * 128 * K;
  const u16* Wp = sg.W + (size_t)nbl * 128 * K;
  const int t = threadIdx.x;
  const int l = t & 63, w = t >> 6;
  const int r0 = t >> 2, c0 = (t & 3) * 8;
  const int wm = (w >> 1) * 64, wn = (w & 1) * 64;
  const int frow = l & 15, fk = (l >> 4) * 8;
  const u16* laf = &la[(wm + frow) * 32 + fk];
  const u16* lbf = &lb[(wn + frow) * 32 + fk];

  const f32x4 vzero = {0.f, 0.f, 0.f, 0.f};
  f32x4 acc[4][4];
#pragma unroll
  for (int i = 0; i < 4; ++i)
#pragma unroll
    for (int j = 0; j < 4; ++j) acc[i][j] = vzero;

  for (int kt = 0; kt < K; kt += 32) {
    async16(Ap + (size_t)r0 * K + kt + c0, ((char*)la) + t * 16);
    async16(Ap + (size_t)(r0 + 64) * K + kt + c0, ((char*)la) + 4096 + t * 16);
    async16(Wp + (size_t)r0 * K + kt + c0, ((char*)lb) + t * 16);
    async16(Wp + (size_t)(r0 + 64) * K + kt + c0, ((char*)lb) + 4096 + t * 16);
    __syncthreads();
    short8 af[4], bfr[4];
#pragma unroll
    for (int i = 0; i < 4; ++i) af[i] = *(const short8*)(laf + i * 512);
#pragma unroll
    for (int j = 0; j < 4; ++j) bfr[j] = *(const short8*)(lbf + j * 512);
#pragma unroll
    for (int i = 0; i < 4; ++i)
#pragma unroll
      for (int j = 0; j < 4; ++j)
        acc[i][j] = __builtin_amdgcn_mfma_f32_16x16x32_bf16(af[i], bfr[j], acc[i][j], 0, 0, 0);
    __syncthreads();
  }

  const int rb = (l >> 4) * 4;
  const int cl = l & 15;
  if (sg.mode == 0) {
    u16* D = (u16*)sg.dst;
#pragma unroll
    for (int i = 0; i < 4; ++i)
#pragma unroll
      for (int j = 0; j < 4; ++j) {
        int col = nbl * 128 + wn + j * 16 + cl;
        float bv = sg.bias[col];
#pragma unroll
        for (int r = 0; r < 4; ++r) {
          int row = mb * 128 + wm + i * 16 + rb + r;
          D[(size_t)row * sg.ldc + col] = f2bf(acc[i][j][r] + bv);
        }
      }
  } else if (sg.mode == 2) {
    float* D = (float*)sg.dst;
#pragma unroll
    for (int i = 0; i < 4; ++i)
#pragma unroll
      for (int j = 0; j < 4; ++j) {
        int col = nbl * 128 + wn + j * 16 + cl;
        float bv = sg.bias[col];
#pragma unroll
        for (int r = 0; r < 4; ++r) {
          int row = mb * 128 + wm + i * 16 + rb + r;
          D[(size_t)row * sg.ldc + col] = acc[i][j][r] + bv;
        }
      }
  } else {
    // V^T pack: output col = h*128+dv, rows are (b,s); write 4 consecutive s as 8B
    u16* D = (u16*)sg.dst;
#pragma unroll
    for (int i = 0; i < 4; ++i) {
      int row0 = mb * 128 + wm + i * 16 + rb;
      int bb = row0 >> 11, ss = row0 & (NS - 1);
#pragma unroll
      for (int j = 0; j < 4; ++j) {
        int col = nbl * 128 + wn + j * 16 + cl;
        int hh = col >> 7, dv = col & 127;
        float bv = sg.bias[col];
        u16 pk[4];
#pragma unroll
        for (int r = 0; r < 4; ++r) pk[r] = f2bf(acc[i][j][r] + bv);
        *(short4v*)(D + ((size_t)((bb * NH + hh) * NDH + dv)) * NS + ss) = *(short4v*)pk;
      }
    }
  }
}

// ---------------- RoPE (in-place, interleaved pairs) ----------------
__global__ __launch_bounds__(256) void rope_kernel(u16* kr, u16* qr) {
  int tid = blockIdx.x * 256 + threadIdx.x;     // 2 * 4096 * 128
  int which = tid >> 19;
  int loc = tid & ((1 << 19) - 1);
  int row = loc >> 7;       // 0..4095 (b*S+s)
  int ch = loc & 127;       // 8-elem chunk within 1024 cols
  int s = row & (NS - 1);
  u16* p = (which ? qr : kr) + (size_t)row * (NH * NDR) + ch * 8;
  short8 v = *(short8*)p;
  int jb = (ch & 7) * 4;    // pair index base within the head (0..31)
  u16 o[8];
#pragma unroll
  for (int q = 0; q < 4; ++q) {
    int j = jb + q;
    float invf = exp2f(-(float)j * 0.41524101186f);  // 10000^(-j/32)
    float ang = (float)s * invf;
    float sn = sinf(ang), cs = cosf(ang);
    float x1 = bf2f(((u16*)&v)[2 * q]);
    float x2 = bf2f(((u16*)&v)[2 * q + 1]);
    o[2 * q]     = f2bf(x1 * cs - x2 * sn);
    o[2 * q + 1] = f2bf(x1 * sn + x2 * cs);
  }
  *(short8*)p = *(short8*)o;
}

// ---------------- flash attention ----------------
__global__ __launch_bounds__(256) void attn_kernel(
    const u16* __restrict__ Qc, const u16* __restrict__ Qr,
    const u16* __restrict__ Kc, const u16* __restrict__ Kr,
    const u16* __restrict__ VT, u16* __restrict__ Ctx) {
  __shared__ u16 kt[64 * 192];     // [key s][d0..191], XOR-swizzled rows (384B)
  __shared__ u16 vt[128 * 64];     // [dv][k], XOR-swizzled rows (128B)
  __shared__ u16 plds[4][16 * 72]; // per-wave P, padded to 72 cols
  const int t = threadIdx.x, w = t >> 6, l = t & 63;
  const int g = l >> 4, cl = l & 15;
  const int bh = blockIdx.y, b = bh >> 4, h = bh & 15;
  const int q0 = blockIdx.x * 64 + w * 16;

  short8 qf[6];
  {
    const u16* qc = Qc + ((size_t)(b * NS + q0 + cl)) * NHID + h * NDH + g * 8;
    qf[0] = *(const short8*)(qc);
    qf[1] = *(const short8*)(qc + 32);
    qf[2] = *(const short8*)(qc + 64);
    qf[3] = *(const short8*)(qc + 96);
    const u16* qr = Qr + ((size_t)(b * NS + q0 + cl)) * (NH * NDR) + h * NDR + g * 8;
    qf[4] = *(const short8*)(qr);
    qf[5] = *(const short8*)(qr + 32);
  }

  const u16* kptr[6]; int kstep[6];
#pragma unroll
  for (int rnd = 0; rnd < 6; ++rnd) {
    int Lb = rnd * 4096 + t * 16;
    int row = Lb / 384;
    int off = Lb - row * 384;
    int c = (off ^ ((row & 7) << 4)) >> 1;
    if (c < NDH) {
      kptr[rnd] = Kc + ((size_t)(b * NS + row)) * NHID + h * NDH + c;
      kstep[rnd] = 64 * NHID;
    } else {
      kptr[rnd] = Kr + ((size_t)(b * NS + row)) * (NH * NDR) + h * NDR + (c - NDH);
      kstep[rnd] = 64 * NH * NDR;
    }
  }
  const u16* vptr[4];
#pragma unroll
  for (int rnd = 0; rnd < 4; ++rnd) {
    int Lb = rnd * 4096 + t * 16;
    int row = Lb >> 7;
    int off = Lb & 127;
    int c = (off ^ ((row & 7) << 4)) >> 1;
    vptr[rnd] = VT + ((size_t)(bh * NDH + row)) * NS + c;
  }

  const f32x4 vzero = {0.f, 0.f, 0.f, 0.f};
  f32x4 o[8];
#pragma unroll
  for (int i = 0; i < 8; ++i) o[i] = vzero;
  float m2[4] = {-INFINITY, -INFINITY, -INFINITY, -INFINITY};
  float lsum[4] = {0.f, 0.f, 0.f, 0.f};
  const float scale2 = 0.10411757f;  // (1/sqrt(192)) * log2(e)
  u16* pl = plds[w];

  for (int kv = 0; kv < NS / 64; ++kv) {
#pragma unroll
    for (int rnd = 0; rnd < 6; ++rnd) {
      async16(kptr[rnd], ((char*)kt) + rnd * 4096 + t * 16);
      kptr[rnd] += kstep[rnd];
    }
#pragma unroll
    for (int rnd = 0; rnd < 4; ++rnd) {
      async16(vptr[rnd], ((char*)vt) + rnd * 4096 + t * 16);
      vptr[rnd] += 64;
    }
    __syncthreads();

    f32x4 sa[4];
#pragma unroll
    for (int n = 0; n < 4; ++n) sa[n] = vzero;
#pragma unroll
    for (int n = 0; n < 4; ++n) {
      int krow = n * 16 + cl;
      const char* kb = ((const char*)kt) + krow * 384;
      int xo = (krow & 7) << 4;
#pragma unroll
      for (int c = 0; c < 6; ++c) {
        short8 kf = *(const short8*)(kb + ((c * 64 + g * 16) ^ xo));
        sa[n] = __builtin_amdgcn_mfma_f32_16x16x32_bf16(qf[c], kf, sa[n], 0, 0, 0);
      }
    }
#pragma unroll
    for (int n = 0; n < 4; ++n) sa[n] = sa[n] * scale2;

    float mx[4];
#pragma unroll
    for (int r = 0; r < 4; ++r)
      mx[r] = fmaxf(fmaxf(sa[0][r], sa[1][r]), fmaxf(sa[2][r], sa[3][r]));
#pragma unroll
    for (int d = 1; d < 16; d <<= 1)
#pragma unroll
      for (int r = 0; r < 4; ++r) mx[r] = fmaxf(mx[r], __shfl_xor(mx[r], d));

    float sf[4], ps[4];
#pragma unroll
    for (int r = 0; r < 4; ++r) {
      float mn = fmaxf(m2[r], mx[r]);
      sf[r] = exp2f(m2[r] - mn);
      m2[r] = mn;
      ps[r] = 0.f;
    }
    u16 pb[16];
#pragma unroll
    for (int n = 0; n < 4; ++n)
#pragma unroll
      for (int r = 0; r < 4; ++r) {
        float p = exp2f(sa[n][r] - m2[r]);
        ps[r] += p;
        pb[n * 4 + r] = f2bf(p);
      }
#pragma unroll
    for (int d = 1; d < 16; d <<= 1)
#pragma unroll
      for (int r = 0; r < 4; ++r) ps[r] += __shfl_xor(ps[r], d);

    f32x4 sfv;
#pragma unroll
    for (int r = 0; r < 4; ++r) { lsum[r] = lsum[r] * sf[r] + ps[r]; sfv[r] = sf[r]; }
#pragma unroll
    for (int n2 = 0; n2 < 8; ++n2) o[n2] = o[n2] * sfv;

#pragma unroll
    for (int n = 0; n < 4; ++n)
#pragma unroll
      for (int r = 0; r < 4; ++r)
        pl[(g * 4 + r) * 72 + n * 16 + cl] = pb[n * 4 + r];

    short8 pa0 = *(const short8*)(pl + cl * 72 + g * 8);
    short8 pa1 = *(const short8*)(pl + cl * 72 + 32 + g * 8);
#pragma unroll
    for (int n2 = 0; n2 < 8; ++n2) {
      int vrow = n2 * 16 + cl;
      const char* vb = ((const char*)vt) + vrow * 128;
      int xo = (vrow & 7) << 4;
      short8 vf0 = *(const short8*)(vb + ((g * 16) ^ xo));
      short8 vf1 = *(const short8*)(vb + ((64 + g * 16) ^ xo));
      o[n2] = __builtin_amdgcn_mfma_f32_16x16x32_bf16(pa0, vf0, o[n2], 0, 0, 0);
      o[n2] = __builtin_amdgcn_mfma_f32_16x16x32_bf16(pa1, vf1, o[n2], 0, 0, 0);
    }
    __syncthreads();
  }

  float inv[4];
#pragma unroll
  for (int r = 0; r < 4; ++r) inv[r] = 1.f / lsum[r];
#pragma unroll
  for (int n2 = 0; n2 < 8; ++n2)
#pragma unroll
    for (int r = 0; r < 4; ++r)
      Ctx[((size_t)(b * NS + q0 + g * 4 + r)) * NHID + h * NDH + n2 * 16 + cl] =
          f2bf(o[n2][r] * inv[r]);
}

// ---------------- host ----------------
extern "C" void kernel_launch(void* const* d_in, const int* in_sizes, int n_in,
                              void* d_out, int out_size, void* d_ws, size_t ws_size,
                              hipStream_t stream) {
  (void)in_sizes; (void)n_in; (void)out_size;
  const float* x      = (const float*)d_in[0];
  const float* d_kv_w = (const float*)d_in[1];
  const float* d_kv_b = (const float*)d_in[2];
  const float* u_k_w  = (const float*)d_in[3];
  const float* u_k_b  = (const float*)d_in[4];
  const float* u_v_w  = (const float*)d_in[5];
  const float* u_v_b  = (const float*)d_in[6];
  const float* d_q_w  = (const float*)d_in[7];
  const float* d_q_b  = (const float*)d_in[8];
  const float* u_q_w  = (const float*)d_in[9];
  const float* u_q_b  = (const float*)d_in[10];
  const float* qr_w   = (const float*)d_in[11];
  const float* qr_b   = (const float*)d_in[12];
  const float* out_w  = (const float*)d_in[13];
  const float* out_b  = (const float*)d_in[14];

  char* ws = (char*)d_ws;
  size_t off = 0;
  auto alloc = [&](size_t bytes) -> void* {
    void* p = ws + off;
    off += (bytes + 255) & ~(size_t)255;
    return p;
  };
  u16* xb   = (u16*)alloc((size_t)NB * NS * NHID * 2);
  u16* wdkv = (u16*)alloc((size_t)NC * NHID * 2);
  u16* wuk  = (u16*)alloc((size_t)NH * NDH * NC * 2);
  u16* wuv  = (u16*)alloc((size_t)NH * NDH * NC * 2);
  u16* wdq  = (u16*)alloc((size_t)NC * NHID * 2);
  u16* wuq  = (u16*)alloc((size_t)NH * NDH * NC * 2);
  u16* wqr  = (u16*)alloc((size_t)NH * NDR * NC * 2);
  u16* wout = (u16*)alloc((size_t)NHID * NH * NDH * 2);
  u16* kvc  = (u16*)alloc((size_t)NB * NS * NC * 2);
  u16* qlat = (u16*)alloc((size_t)NB * NS * NC * 2);
  u16* Kc   = (u16*)alloc((size_t)NB * NS * NH * NDH * 2);
  u16* Krt  = (u16*)alloc((size_t)NB * NS * NH * NDR * 2);
  u16* Qc   = (u16*)alloc((size_t)NB * NS * NH * NDH * 2);
  u16* Qrt  = (u16*)alloc((size_t)NB * NS * NH * NDR * 2);
  u16* VT   = (u16*)alloc((size_t)NB * NH * NDH * NS * 2);
  u16* ctx  = xb;  // alias: x (bf16) dead after latent GEMM
  if (off > ws_size) return;

  // 1) cast
  {
    CastArgs ca;
    const float* srcs[8] = {x, d_kv_w, u_k_w, u_v_w, d_q_w, u_q_w, qr_w, out_w};
    u16* dsts[8] = {xb, wdkv, wuk, wuv, wdq, wuq, wqr, wout};
    int sizes[8] = {NB * NS * NHID, NC * NHID, NH * NDH * NC, NH * NDH * NC,
                    NC * NHID, NH * NDH * NC, NH * NDR * NC, NHID * NH * NDH};
    int st = 0;
    for (int i = 0; i < 8; ++i) {
      ca.src[i] = srcs[i]; ca.dst[i] = dsts[i]; ca.start[i] = st;
      st += sizes[i] / 2048;
    }
    cast_kernel<<<dim3(st), dim3(256), 0, stream>>>(ca);
  }

  // 2) latent GEMM: kv_c and q_lat (K=2048, N=512 each)
  {
    GemmArgs ga;
    ga.nseg = 2;
    ga.seg[0] = {xb, wdkv, d_kv_b, kvc, NHID, 0, NC};
    ga.seg[1] = {xb, wdq,  d_q_b,  qlat, NHID, 0, NC};
    for (int i = 2; i < 5; ++i) ga.seg[i] = ga.seg[0];
    ga.nbstart[0] = 0; ga.nbstart[1] = 4; ga.nbstart[2] = 8;
    ga.nbstart[3] = 8; ga.nbstart[4] = 8; ga.nbstart[5] = 8;
    gemm_bt<<<dim3(8, 32), dim3(256), 0, stream>>>(ga);
  }

  // 3) up GEMMs: k_c, v(->V^T), k_r, q_c, q_r (K=512)
  {
    GemmArgs ga;
    ga.nseg = 5;
    ga.seg[0] = {kvc,  wuk, u_k_b, Kc,  NC, 0, NH * NDH};
    ga.seg[1] = {kvc,  wuv, u_v_b, VT,  NC, 1, 0};
    ga.seg[2] = {kvc,  wqr, qr_b,  Krt, NC, 0, NH * NDR};
    ga.seg[3] = {qlat, wuq, u_q_b, Qc,  NC, 0, NH * NDH};
    ga.seg[4] = {qlat, wqr, qr_b,  Qrt, NC, 0, NH * NDR};
    ga.nbstart[0] = 0;  ga.nbstart[1] = 16; ga.nbstart[2] = 32;
    ga.nbstart[3] = 40; ga.nbstart[4] = 56; ga.nbstart[5] = 64;
    gemm_bt<<<dim3(64, 32), dim3(256), 0, stream>>>(ga);
  }

  // 4) RoPE in-place on Krt and Qrt
  rope_kernel<<<dim3(4096), dim3(256), 0, stream>>>(Krt, Qrt);

  // 5) attention
  attn_kernel<<<dim3(32, 32), dim3(256), 0, stream>>>(Qc, Qrt, Kc, Krt, VT, ctx);

  // 6) out projection (f32 out + bias)
  {
    GemmArgs ga;
    ga.nseg = 1;
    ga.seg[0] = {ctx, wout, out_b, d_out, NHID, 2, NHID};
    for (int i = 1; i < 5; ++i) ga.seg[i] = ga.seg[0];
    ga.nbstart[0] = 0;
    for (int i = 1; i < 6; ++i) ga.nbstart[i] = 16;
    gemm_bt<<<dim3(16, 32), dim3(256), 0, stream>>>(ga);
  }
}

// Round 2
// 313.392 us; speedup vs baseline: 1.2356x; 1.2356x over previous
//
#include <hip/hip_runtime.h>
#include <hip/hip_bf16.h>
#include <math.h>
#include <stdint.h>

#define NB 2
#define NS 2048
#define NH 16
#define NDH 128
#define NDR 64
#define NHID 2048
#define NC 512

typedef unsigned short u16;
typedef short short8 __attribute__((ext_vector_type(8)));
typedef short short4v __attribute__((ext_vector_type(4)));
typedef float f32x4 __attribute__((ext_vector_type(4)));

__device__ __forceinline__ u16 f2bf(float f) {
  union { float f; uint32_t u; } c; c.f = f;
  uint32_t u = c.u + 0x7fffu + ((c.u >> 16) & 1u);
  return (u16)(u >> 16);
}
__device__ __forceinline__ float bf2f(u16 b) {
  union { uint32_t u; float f; } c; c.u = ((uint32_t)b) << 16;
  return c.f;
}
__device__ __forceinline__ void async16(const void* g, void* l) {
  __builtin_amdgcn_global_load_lds((const __attribute__((address_space(1))) void*)g,
                                   (__attribute__((address_space(3))) void*)l, 16, 0, 0);
}
__device__ __forceinline__ uint32_t cvtpk(float a, float b) {
  uint32_t r;
  asm("v_cvt_pk_bf16_f32 %0, %1, %2" : "=v"(r) : "v"(a), "v"(b));
  return r;
}

// ---------------- cast f32 -> bf16 ----------------
struct CastArgs {
  const float* src[8];
  u16* dst[8];
  int start[8];   // block prefix starts
};

__global__ __launch_bounds__(256) void cast_kernel(CastArgs a) {
  int blk = blockIdx.x;
  int ti = 0;
#pragma unroll
  for (int i = 1; i < 8; ++i) ti += (blk >= a.start[i]) ? 1 : 0;
  size_t off = (size_t)(blk - a.start[ti]) * 2048 + (size_t)threadIdx.x * 8;
  const float4* s = (const float4*)(a.src[ti] + off);
  float4 v0 = s[0], v1 = s[1];
  u16 o[8];
  o[0] = f2bf(v0.x); o[1] = f2bf(v0.y); o[2] = f2bf(v0.z); o[3] = f2bf(v0.w);
  o[4] = f2bf(v1.x); o[5] = f2bf(v1.y); o[6] = f2bf(v1.z); o[7] = f2bf(v1.w);
  *(short8*)(a.dst[ti] + off) = *(short8*)o;
}

// ---------------- generic B^T GEMM (bf16 MFMA, f32 acc) ----------------
struct GemmSeg {
  const u16* A;
  const u16* W;
  const float* bias;
  void* dst;
  int K;
  int mode;   // 0: bf16 rowmajor [M][ldc]; 1: V^T pack -> [b][h][dv][s]; 2: f32 rowmajor
  int ldc;
};
struct GemmArgs {
  GemmSeg seg[5];
  int nbstart[6];
  int nseg;
};

__global__ __launch_bounds__(256) void gemm_bt(GemmArgs ga) {
  __shared__ u16 la[128 * 32];
  __shared__ u16 lb[128 * 32];
  const int nb = blockIdx.x, mb = blockIdx.y;
  int si = 0;
  for (int i = 1; i < ga.nseg; ++i) si += (nb >= ga.nbstart[i]) ? 1 : 0;
  GemmSeg sg = ga.seg[si];
  const int nbl = nb - ga.nbstart[si];
  const int K = sg.K;
  const u16* Ap = sg.A + (size_t)mb * 128 * K;
  const u16* Wp = sg.W + (size_t)nbl * 128 * K;
  const int t = threadIdx.x;
  const int l = t & 63, w = t >> 6;
  const int r0 = t >> 2, c0 = (t & 3) * 8;
  const int wm = (w >> 1) * 64, wn = (w & 1) * 64;
  const int frow = l & 15, fk = (l >> 4) * 8;
  const u16* laf = &la[(wm + frow) * 32 + fk];
  const u16* lbf = &lb[(wn + frow) * 32 + fk];

  const f32x4 vzero = {0.f, 0.f, 0.f, 0.f};
  f32x4 acc[4][4];
#pragma unroll
  for (int i = 0; i < 4; ++i)
#pragma unroll
    for (int j = 0; j < 4; ++j) acc[i][j] = vzero;

  for (int kt = 0; kt < K; kt += 32) {
    async16(Ap + (size_t)r0 * K + kt + c0, ((char*)la) + t * 16);
    async16(Ap + (size_t)(r0 + 64) * K + kt + c0, ((char*)la) + 4096 + t * 16);
    async16(Wp + (size_t)r0 * K + kt + c0, ((char*)lb) + t * 16);
    async16(Wp + (size_t)(r0 + 64) * K + kt + c0, ((char*)lb) + 4096 + t * 16);
    __syncthreads();
    short8 af[4], bfr[4];
#pragma unroll
    for (int i = 0; i < 4; ++i) af[i] = *(const short8*)(laf + i * 512);
#pragma unroll
    for (int j = 0; j < 4; ++j) bfr[j] = *(const short8*)(lbf + j * 512);
#pragma unroll
    for (int i = 0; i < 4; ++i)
#pragma unroll
      for (int j = 0; j < 4; ++j)
        acc[i][j] = __builtin_amdgcn_mfma_f32_16x16x32_bf16(af[i], bfr[j], acc[i][j], 0, 0, 0);
    __syncthreads();
  }

  const int rb = (l >> 4) * 4;
  const int cl = l & 15;
  if (sg.mode == 0) {
    u16* D = (u16*)sg.dst;
#pragma unroll
    for (int i = 0; i < 4; ++i)
#pragma unroll
      for (int j = 0; j < 4; ++j) {
        int col = nbl * 128 + wn + j * 16 + cl;
        float bv = sg.bias[col];
#pragma unroll
        for (int r = 0; r < 4; ++r) {
          int row = mb * 128 + wm + i * 16 + rb + r;
          D[(size_t)row * sg.ldc + col] = f2bf(acc[i][j][r] + bv);
        }
      }
  } else if (sg.mode == 2) {
    float* D = (float*)sg.dst;
#pragma unroll
    for (int i = 0; i < 4; ++i)
#pragma unroll
      for (int j = 0; j < 4; ++j) {
        int col = nbl * 128 + wn + j * 16 + cl;
        float bv = sg.bias[col];
#pragma unroll
        for (int r = 0; r < 4; ++r) {
          int row = mb * 128 + wm + i * 16 + rb + r;
          D[(size_t)row * sg.ldc + col] = acc[i][j][r] + bv;
        }
      }
  } else {
    u16* D = (u16*)sg.dst;
#pragma unroll
    for (int i = 0; i < 4; ++i) {
      int row0 = mb * 128 + wm + i * 16 + rb;
      int bb = row0 >> 11, ss = row0 & (NS - 1);
#pragma unroll
      for (int j = 0; j < 4; ++j) {
        int col = nbl * 128 + wn + j * 16 + cl;
        int hh = col >> 7, dv = col & 127;
        float bv = sg.bias[col];
        u16 pk[4];
#pragma unroll
        for (int r = 0; r < 4; ++r) pk[r] = f2bf(acc[i][j][r] + bv);
        *(short4v*)(D + ((size_t)((bb * NH + hh) * NDH + dv)) * NS + ss) = *(short4v*)pk;
      }
    }
  }
}

// ---------------- RoPE (in-place, interleaved pairs) ----------------
__global__ __launch_bounds__(256) void rope_kernel(u16* kr, u16* qr) {
  int tid = blockIdx.x * 256 + threadIdx.x;     // 2 * 4096 * 128
  int which = tid >> 19;
  int loc = tid & ((1 << 19) - 1);
  int row = loc >> 7;       // 0..4095 (b*S+s)
  int ch = loc & 127;       // 8-elem chunk within 1024 cols
  int s = row & (NS - 1);
  u16* p = (which ? qr : kr) + (size_t)row * (NH * NDR) + ch * 8;
  short8 v = *(short8*)p;
  int jb = (ch & 7) * 4;    // pair index base within the head (0..31)
  u16 o[8];
#pragma unroll
  for (int q = 0; q < 4; ++q) {
    int j = jb + q;
    float invf = exp2f(-(float)j * 0.41524101186f);  // 10000^(-j/32)
    float ang = (float)s * invf;
    float sn = sinf(ang), cs = cosf(ang);
    float x1 = bf2f(((u16*)&v)[2 * q]);
    float x2 = bf2f(((u16*)&v)[2 * q + 1]);
    o[2 * q]     = f2bf(x1 * cs - x2 * sn);
    o[2 * q + 1] = f2bf(x1 * sn + x2 * cs);
  }
  *(short8*)p = *(short8*)o;
}

// ---------------- flash attention (swapped QK^T, in-register P) ----------------
// Block: 4 waves x 32 q-rows = 128 q. Double-buffered K/V in 80KB dynamic LDS.
// S^T = mfma(K, Q): lane (g=l>>4, cl=l&15) holds P[k = n*16+g*4+r][q = cl].
// PV: O^T = mfma16x16x16(V^T-frag, P^T-frag): lane's own p-values ARE the K=16 B-frag.
__global__ __launch_bounds__(256, 2) void attn_kernel(
    const u16* __restrict__ Qc, const u16* __restrict__ Qr,
    const u16* __restrict__ Kc, const u16* __restrict__ Kr,
    const u16* __restrict__ VT, u16* __restrict__ Ctx) {
  extern __shared__ char smem[];   // 2 x (24576 K + 16384 V) = 81920
  const int t = threadIdx.x, w = t >> 6, l = t & 63;
  const int g = l >> 4, cl = l & 15;
  // bijective XCD swizzle: each XCD gets 4 consecutive bh (K/V L2 locality)
  const int lin = blockIdx.x;
  const int xcd = lin & 7, idx = lin >> 3;
  const int bh = xcd * 4 + (idx >> 4);
  const int qb = idx & 15;
  const int b = bh >> 4, h = bh & 15;
  const int q0 = qb * 128 + w * 32;

  // Q fragments: B-operand layout = lane holds col q=cl, k-dim bytes g*16
  short8 qf[2][6];
#pragma unroll
  for (int qr = 0; qr < 2; ++qr) {
    const u16* qc = Qc + ((size_t)(b * NS + q0 + qr * 16 + cl)) * NHID + h * NDH + g * 8;
    const u16* qrp = Qr + ((size_t)(b * NS + q0 + qr * 16 + cl)) * (NH * NDR) + h * NDR + g * 8;
#pragma unroll
    for (int c = 0; c < 4; ++c) qf[qr][c] = *(const short8*)(qc + c * 32);
    qf[qr][4] = *(const short8*)(qrp);
    qf[qr][5] = *(const short8*)(qrp + 32);
  }
  // force materialization so the compiler's waitcnt for these lands BEFORE the loop
#pragma unroll
  for (int qr = 0; qr < 2; ++qr)
#pragma unroll
    for (int c = 0; c < 6; ++c) asm volatile("" :: "v"(qf[qr][c]));

  // staging pointers (inverse-swizzled global source, linear LDS dest)
  const u16* kptr[6]; int kstep[6];
#pragma unroll
  for (int r = 0; r < 6; ++r) {
    int Lb = r * 4096 + t * 16;
    int row = Lb / 384;
    int off = Lb - row * 384;
    int c = (off ^ ((row & 7) << 4)) >> 1;
    if (c < NDH) { kptr[r] = Kc + ((size_t)(b * NS + row)) * NHID + h * NDH + c; kstep[r] = 64 * NHID; }
    else { kptr[r] = Kr + ((size_t)(b * NS + row)) * (NH * NDR) + h * NDR + (c - NDH); kstep[r] = 64 * NH * NDR; }
  }
  const u16* vptr[4];
#pragma unroll
  for (int r = 0; r < 4; ++r) {
    int Lb = r * 4096 + t * 16;
    int row = Lb >> 7, off = Lb & 127;
    int c = (off ^ ((row & 7) << 4)) >> 1;
    vptr[r] = VT + ((size_t)(bh * NDH + row)) * NS + c;
  }

  float m2[2] = {-1e30f, -1e30f};
  float lsum[2] = {0.f, 0.f};
  const f32x4 vzero = {0.f, 0.f, 0.f, 0.f};
  f32x4 o[2][8];
#pragma unroll
  for (int qr = 0; qr < 2; ++qr)
#pragma unroll
    for (int d = 0; d < 8; ++d) o[qr][d] = vzero;
  const float scale2 = 0.10411757f;  // (1/sqrt(192)) * log2(e)

  // prologue: stage tile 0 into buf 0
  {
    char* base = smem;
#pragma unroll
    for (int r = 0; r < 6; ++r) { async16(kptr[r], base + r * 4096 + t * 16); kptr[r] += kstep[r]; }
#pragma unroll
    for (int r = 0; r < 4; ++r) { async16(vptr[r], base + 24576 + r * 4096 + t * 16); vptr[r] += 64; }
  }

  for (int kv = 0; kv < NS / 64; ++kv) {
    const char* cur = smem + (size_t)(kv & 1) * 40960;
    if (kv < NS / 64 - 1) {
      char* nxt = smem + (size_t)((kv + 1) & 1) * 40960;
#pragma unroll
      for (int r = 0; r < 6; ++r) { async16(kptr[r], nxt + r * 4096 + t * 16); kptr[r] += kstep[r]; }
#pragma unroll
      for (int r = 0; r < 4; ++r) { async16(vptr[r], nxt + 24576 + r * 4096 + t * 16); vptr[r] += 64; }
      asm volatile("s_waitcnt vmcnt(10)" ::: "memory");   // wait current tile only
    } else {
      asm volatile("s_waitcnt vmcnt(0)" ::: "memory");
    }
    __builtin_amdgcn_s_barrier();
    asm volatile("" ::: "memory");

    const u16* kt = (const u16*)cur;
    const u16* vt = (const u16*)(cur + 24576);

    // QK^T (swapped): sa[qr][n], rows k = n*16+g*4+r, col q = cl
    f32x4 sa[2][4];
#pragma unroll
    for (int qr = 0; qr < 2; ++qr)
#pragma unroll
      for (int n = 0; n < 4; ++n) sa[qr][n] = vzero;
#pragma unroll
    for (int n = 0; n < 4; ++n) {
      int krow = n * 16 + cl;
      const char* kb = ((const char*)kt) + krow * 384;
      int xo = (krow & 7) << 4;
      short8 kf[6];
#pragma unroll
      for (int c = 0; c < 6; ++c) kf[c] = *(const short8*)(kb + ((c * 64 + g * 16) ^ xo));
      __builtin_amdgcn_s_setprio(1);
#pragma unroll
      for (int c = 0; c < 6; ++c) {
        sa[0][n] = __builtin_amdgcn_mfma_f32_16x16x32_bf16(kf[c], qf[0][c], sa[0][n], 0, 0, 0);
        sa[1][n] = __builtin_amdgcn_mfma_f32_16x16x32_bf16(kf[c], qf[1][c], sa[1][n], 0, 0, 0);
      }
      __builtin_amdgcn_s_setprio(0);
    }

    // in-lane online softmax per q-group
    short4v pb[2][4];
#pragma unroll
    for (int qr = 0; qr < 2; ++qr) {
      float mx = fmaxf(fmaxf(sa[qr][0][0], sa[qr][0][1]), fmaxf(sa[qr][0][2], sa[qr][0][3]));
#pragma unroll
      for (int n = 1; n < 4; ++n)
        mx = fmaxf(mx, fmaxf(fmaxf(sa[qr][n][0], sa[qr][n][1]), fmaxf(sa[qr][n][2], sa[qr][n][3])));
      mx = fmaxf(mx, __shfl_xor(mx, 16));
      mx = fmaxf(mx, __shfl_xor(mx, 32));
      float mxs = mx * scale2;
      if (!__all(mxs <= m2[qr] + 6.0f)) {       // defer-max (T13)
        float mn = fmaxf(m2[qr], mxs);
        float sf = exp2f(m2[qr] - mn);
        m2[qr] = mn;
        lsum[qr] *= sf;
        f32x4 sfv = {sf, sf, sf, sf};
#pragma unroll
        for (int d = 0; d < 8; ++d) o[qr][d] *= sfv;
      }
      float nm = -m2[qr];
      float ps = 0.f;
#pragma unroll
      for (int n = 0; n < 4; ++n) {
        float p0 = exp2f(fmaf(sa[qr][n][0], scale2, nm));
        float p1 = exp2f(fmaf(sa[qr][n][1], scale2, nm));
        float p2 = exp2f(fmaf(sa[qr][n][2], scale2, nm));
        float p3 = exp2f(fmaf(sa[qr][n][3], scale2, nm));
        ps += (p0 + p1) + (p2 + p3);
        union { uint32_t u[2]; short4v s; } pu;
        pu.u[0] = cvtpk(p0, p1);
        pu.u[1] = cvtpk(p2, p3);
        pb[qr][n] = pu.s;
      }
      ps += __shfl_xor(ps, 16);
      ps += __shfl_xor(ps, 32);
      lsum[qr] += ps;
    }

    // PV: O^T[dv][q] += V^T-frag x P^T-frag (K=16 per n-step)
#pragma unroll
    for (int n = 0; n < 4; ++n) {
      __builtin_amdgcn_s_setprio(1);
#pragma unroll
      for (int d = 0; d < 8; ++d) {
        int vrow = d * 16 + cl;
        const char* vb = ((const char*)vt) + vrow * 128;
        short4v va = *(const short4v*)(vb + ((n * 32 + g * 8) ^ ((vrow & 7) << 4)));
        o[0][d] = __builtin_amdgcn_mfma_f32_16x16x16bf16_1k(va, pb[0][n], o[0][d], 0, 0, 0);
        o[1][d] = __builtin_amdgcn_mfma_f32_16x16x16bf16_1k(va, pb[1][n], o[1][d], 0, 0, 0);
      }
      __builtin_amdgcn_s_setprio(0);
    }

    asm volatile("s_waitcnt lgkmcnt(0)" ::: "memory");  // drain ds_reads before buffer reuse
    __builtin_amdgcn_s_barrier();
  }

  // epilogue: normalize + store (4 consecutive dv per lane -> 8B stores)
#pragma unroll
  for (int qr = 0; qr < 2; ++qr) {
    float invq = 1.f / lsum[qr];
    u16* dst = Ctx + ((size_t)(b * NS + q0 + qr * 16 + cl)) * NHID + h * NDH + g * 4;
#pragma unroll
    for (int d = 0; d < 8; ++d) {
      float a0 = o[qr][d][0] * invq, a1 = o[qr][d][1] * invq;
      float a2 = o[qr][d][2] * invq, a3 = o[qr][d][3] * invq;
      union { uint32_t u[2]; short4v s; } pu;
      pu.u[0] = cvtpk(a0, a1);
      pu.u[1] = cvtpk(a2, a3);
      *(short4v*)(dst + d * 16) = pu.s;
    }
  }
}

// ---------------- host ----------------
extern "C" void kernel_launch(void* const* d_in, const int* in_sizes, int n_in,
                              void* d_out, int out_size, void* d_ws, size_t ws_size,
                              hipStream_t stream) {
  (void)in_sizes; (void)n_in; (void)out_size;
  const float* x      = (const float*)d_in[0];
  const float* d_kv_w = (const float*)d_in[1];
  const float* d_kv_b = (const float*)d_in[2];
  const float* u_k_w  = (const float*)d_in[3];
  const float* u_k_b  = (const float*)d_in[4];
  const float* u_v_w  = (const float*)d_in[5];
  const float* u_v_b  = (const float*)d_in[6];
  const float* d_q_w  = (const float*)d_in[7];
  const float* d_q_b  = (const float*)d_in[8];
  const float* u_q_w  = (const float*)d_in[9];
  const float* u_q_b  = (const float*)d_in[10];
  const float* qr_w   = (const float*)d_in[11];
  const float* qr_b   = (const float*)d_in[12];
  const float* out_w  = (const float*)d_in[13];
  const float* out_b  = (const float*)d_in[14];

  char* ws = (char*)d_ws;
  size_t off = 0;
  auto alloc = [&](size_t bytes) -> void* {
    void* p = ws + off;
    off += (bytes + 255) & ~(size_t)255;
    return p;
  };
  u16* xb   = (u16*)alloc((size_t)NB * NS * NHID * 2);
  u16* wdkv = (u16*)alloc((size_t)NC * NHID * 2);
  u16* wuk  = (u16*)alloc((size_t)NH * NDH * NC * 2);
  u16* wuv  = (u16*)alloc((size_t)NH * NDH * NC * 2);
  u16* wdq  = (u16*)alloc((size_t)NC * NHID * 2);
  u16* wuq  = (u16*)alloc((size_t)NH * NDH * NC * 2);
  u16* wqr  = (u16*)alloc((size_t)NH * NDR * NC * 2);
  u16* wout = (u16*)alloc((size_t)NHID * NH * NDH * 2);
  u16* kvc  = (u16*)alloc((size_t)NB * NS * NC * 2);
  u16* qlat = (u16*)alloc((size_t)NB * NS * NC * 2);
  u16* Kc   = (u16*)alloc((size_t)NB * NS * NH * NDH * 2);
  u16* Krt  = (u16*)alloc((size_t)NB * NS * NH * NDR * 2);
  u16* Qc   = (u16*)alloc((size_t)NB * NS * NH * NDH * 2);
  u16* Qrt  = (u16*)alloc((size_t)NB * NS * NH * NDR * 2);
  u16* VT   = (u16*)alloc((size_t)NB * NH * NDH * NS * 2);
  u16* ctx  = xb;  // alias: x (bf16) dead after latent GEMM
  if (off > ws_size) return;

  // 1) cast
  {
    CastArgs ca;
    const float* srcs[8] = {x, d_kv_w, u_k_w, u_v_w, d_q_w, u_q_w, qr_w, out_w};
    u16* dsts[8] = {xb, wdkv, wuk, wuv, wdq, wuq, wqr, wout};
    int sizes[8] = {NB * NS * NHID, NC * NHID, NH * NDH * NC, NH * NDH * NC,
                    NC * NHID, NH * NDH * NC, NH * NDR * NC, NHID * NH * NDH};
    int st = 0;
    for (int i = 0; i < 8; ++i) {
      ca.src[i] = srcs[i]; ca.dst[i] = dsts[i]; ca.start[i] = st;
      st += sizes[i] / 2048;
    }
    cast_kernel<<<dim3(st), dim3(256), 0, stream>>>(ca);
  }

  // 2) latent GEMM: kv_c and q_lat (K=2048, N=512 each)
  {
    GemmArgs ga;
    ga.nseg = 2;
    ga.seg[0] = {xb, wdkv, d_kv_b, kvc, NHID, 0, NC};
    ga.seg[1] = {xb, wdq,  d_q_b,  qlat, NHID, 0, NC};
    for (int i = 2; i < 5; ++i) ga.seg[i] = ga.seg[0];
    ga.nbstart[0] = 0; ga.nbstart[1] = 4; ga.nbstart[2] = 8;
    ga.nbstart[3] = 8; ga.nbstart[4] = 8; ga.nbstart[5] = 8;
    gemm_bt<<<dim3(8, 32), dim3(256), 0, stream>>>(ga);
  }

  // 3) up GEMMs: k_c, v(->V^T), k_r, q_c, q_r (K=512)
  {
    GemmArgs ga;
    ga.nseg = 5;
    ga.seg[0] = {kvc,  wuk, u_k_b, Kc,  NC, 0, NH * NDH};
    ga.seg[1] = {kvc,  wuv, u_v_b, VT,  NC, 1, 0};
    ga.seg[2] = {kvc,  wqr, qr_b,  Krt, NC, 0, NH * NDR};
    ga.seg[3] = {qlat, wuq, u_q_b, Qc,  NC, 0, NH * NDH};
    ga.seg[4] = {qlat, wqr, qr_b,  Qrt, NC, 0, NH * NDR};
    ga.nbstart[0] = 0;  ga.nbstart[1] = 16; ga.nbstart[2] = 32;
    ga.nbstart[3] = 40; ga.nbstart[4] = 56; ga.nbstart[5] = 64;
    gemm_bt<<<dim3(64, 32), dim3(256), 0, stream>>>(ga);
  }

  // 4) RoPE in-place on Krt and Qrt
  rope_kernel<<<dim3(4096), dim3(256), 0, stream>>>(Krt, Qrt);

  // 5) attention (80KB dynamic LDS, 2 blocks/CU)
  hipFuncSetAttribute((const void*)attn_kernel,
                      hipFuncAttributeMaxDynamicSharedMemorySize, 81920);
  attn_kernel<<<dim3(512), dim3(256), 81920, stream>>>(Qc, Qrt, Kc, Krt, VT, ctx);

  // 6) out projection (f32 out + bias)
  {
    GemmArgs ga;
    ga.nseg = 1;
    ga.seg[0] = {ctx, wout, out_b, d_out, NHID, 2, NHID};
    for (int i = 1; i < 5; ++i) ga.seg[i] = ga.seg[0];
    ga.nbstart[0] = 0;
    for (int i = 1; i < 6; ++i) ga.nbstart[i] = 16;
    gemm_bt<<<dim3(16, 32), dim3(256), 0, stream>>>(ga);
  }
}

// Round 3
// 303.663 us; speedup vs baseline: 1.2752x; 1.0320x over previous
//
#include <hip/hip_runtime.h>
#include <hip/hip_bf16.h>
#include <math.h>
#include <stdint.h>

#define NB 2
#define NS 2048
#define NH 16
#define NDH 128
#define NDR 64
#define NHID 2048
#define NC 512

typedef unsigned short u16;
typedef short short8 __attribute__((ext_vector_type(8)));
typedef short short4v __attribute__((ext_vector_type(4)));
typedef float f32x4 __attribute__((ext_vector_type(4)));

template <int V> struct IC { static constexpr int value = V; };

__device__ __forceinline__ u16 f2bf(float f) {
  union { float f; uint32_t u; } c; c.f = f;
  uint32_t u = c.u + 0x7fffu + ((c.u >> 16) & 1u);
  return (u16)(u >> 16);
}
__device__ __forceinline__ float bf2f(u16 b) {
  union { uint32_t u; float f; } c; c.u = ((uint32_t)b) << 16;
  return c.f;
}
__device__ __forceinline__ void async16(const void* g, void* l) {
  __builtin_amdgcn_global_load_lds((const __attribute__((address_space(1))) void*)g,
                                   (__attribute__((address_space(3))) void*)l, 16, 0, 0);
}
__device__ __forceinline__ uint32_t cvtpk(float a, float b) {
  uint32_t r;
  asm("v_cvt_pk_bf16_f32 %0, %1, %2" : "=v"(r) : "v"(a), "v"(b));
  return r;
}

// ---------------- cast f32 -> bf16 ----------------
struct CastArgs {
  const float* src[8];
  u16* dst[8];
  int start[8];
};

__global__ __launch_bounds__(256) void cast_kernel(CastArgs a) {
  int blk = blockIdx.x;
  int ti = 0;
#pragma unroll
  for (int i = 1; i < 8; ++i) ti += (blk >= a.start[i]) ? 1 : 0;
  size_t off = (size_t)(blk - a.start[ti]) * 2048 + (size_t)threadIdx.x * 8;
  const float4* s = (const float4*)(a.src[ti] + off);
  float4 v0 = s[0], v1 = s[1];
  u16 o[8];
  o[0] = f2bf(v0.x); o[1] = f2bf(v0.y); o[2] = f2bf(v0.z); o[3] = f2bf(v0.w);
  o[4] = f2bf(v1.x); o[5] = f2bf(v1.y); o[6] = f2bf(v1.z); o[7] = f2bf(v1.w);
  *(short8*)(a.dst[ti] + off) = *(short8*)o;
}

// ---------------- generic B^T GEMM, 2-phase pipelined ----------------
struct GemmSeg {
  const u16* A;
  const u16* W;
  const float* bias;
  void* dst;
  int K;
  int mode;   // 0: bf16 rowmajor; 1: V^T pack -> [b][h][dv][s]; 2: f32 rowmajor
  int ldc;
};
struct GemmArgs {
  GemmSeg seg[5];
  int nbstart[6];
  int nseg;
};

__global__ __launch_bounds__(256) void gemm_bt(GemmArgs ga) {
  __shared__ char glds[32768];   // [buf(16K)][A(8K)|B(8K)]
  const int nb = blockIdx.x, mb = blockIdx.y;
  int si = 0;
  for (int i = 1; i < ga.nseg; ++i) si += (nb >= ga.nbstart[i]) ? 1 : 0;
  GemmSeg sg = ga.seg[si];
  const int nbl = nb - ga.nbstart[si];
  const int K = sg.K;
  const int t = threadIdx.x;
  const int l = t & 63, w = t >> 6;
  const int r0 = t >> 2, c0 = (t & 3) * 8;
  const int wm = (w >> 1) * 64, wn = (w & 1) * 64;
  const int frow = l & 15, fk = (l >> 4) * 8;
  const int lafO = ((wm + frow) * 32 + fk) * 2;
  const int lbfO = 8192 + ((wn + frow) * 32 + fk) * 2;

  const u16* apA = sg.A + (size_t)mb * 128 * K + (size_t)r0 * K + c0;
  const u16* wpA = sg.W + (size_t)nbl * 128 * K + (size_t)r0 * K + c0;

  auto stage = [&](int bufOff) {
    async16(apA, glds + bufOff + t * 16);
    async16(apA + (size_t)64 * K, glds + bufOff + 4096 + t * 16);
    async16(wpA, glds + bufOff + 8192 + t * 16);
    async16(wpA + (size_t)64 * K, glds + bufOff + 12288 + t * 16);
    apA += 32; wpA += 32;
  };

  const f32x4 vzero = {0.f, 0.f, 0.f, 0.f};
  f32x4 acc[4][4];
#pragma unroll
  for (int i = 0; i < 4; ++i)
#pragma unroll
    for (int j = 0; j < 4; ++j) acc[i][j] = vzero;

  stage(0);
  const int nk = K / 32;   // even for all segments (16 or 64)

  auto ktile = [&](auto bufc, bool stageNext) {
    constexpr int BO = decltype(bufc)::value;
    if (stageNext) {
      stage(BO ^ 16384);
      asm volatile("s_waitcnt vmcnt(4)" ::: "memory");
    } else {
      asm volatile("s_waitcnt vmcnt(0)" ::: "memory");
    }
    __builtin_amdgcn_s_barrier();
    asm volatile("" ::: "memory");
    short8 af[4], bfr[4];
#pragma unroll
    for (int i = 0; i < 4; ++i) af[i] = *(const short8*)(glds + BO + lafO + i * 1024);
#pragma unroll
    for (int j = 0; j < 4; ++j) bfr[j] = *(const short8*)(glds + BO + lbfO + j * 1024);
    __builtin_amdgcn_s_setprio(1);
#pragma unroll
    for (int i = 0; i < 4; ++i)
#pragma unroll
      for (int j = 0; j < 4; ++j)
        acc[i][j] = __builtin_amdgcn_mfma_f32_16x16x32_bf16(af[i], bfr[j], acc[i][j], 0, 0, 0);
    __builtin_amdgcn_s_setprio(0);
    asm volatile("s_waitcnt lgkmcnt(0)" ::: "memory");
    __builtin_amdgcn_s_barrier();
  };

  for (int kk = 0; kk < nk; kk += 2) {
    ktile(IC<0>{}, true);
    ktile(IC<16384>{}, kk + 2 < nk);
  }

  const int rb = (l >> 4) * 4;
  const int cl = l & 15;
  if (sg.mode == 0) {
    u16* D = (u16*)sg.dst;
#pragma unroll
    for (int i = 0; i < 4; ++i)
#pragma unroll
      for (int j = 0; j < 4; ++j) {
        int col = nbl * 128 + wn + j * 16 + cl;
        float bv = sg.bias[col];
#pragma unroll
        for (int r = 0; r < 4; ++r) {
          int row = mb * 128 + wm + i * 16 + rb + r;
          D[(size_t)row * sg.ldc + col] = f2bf(acc[i][j][r] + bv);
        }
      }
  } else if (sg.mode == 2) {
    float* D = (float*)sg.dst;
#pragma unroll
    for (int i = 0; i < 4; ++i)
#pragma unroll
      for (int j = 0; j < 4; ++j) {
        int col = nbl * 128 + wn + j * 16 + cl;
        float bv = sg.bias[col];
#pragma unroll
        for (int r = 0; r < 4; ++r) {
          int row = mb * 128 + wm + i * 16 + rb + r;
          D[(size_t)row * sg.ldc + col] = acc[i][j][r] + bv;
        }
      }
  } else {
    u16* D = (u16*)sg.dst;
#pragma unroll
    for (int i = 0; i < 4; ++i) {
      int row0 = mb * 128 + wm + i * 16 + rb;
      int bb = row0 >> 11, ss = row0 & (NS - 1);
#pragma unroll
      for (int j = 0; j < 4; ++j) {
        int col = nbl * 128 + wn + j * 16 + cl;
        int hh = col >> 7, dv = col & 127;
        float bv = sg.bias[col];
        u16 pk[4];
#pragma unroll
        for (int r = 0; r < 4; ++r) pk[r] = f2bf(acc[i][j][r] + bv);
        *(short4v*)(D + ((size_t)((bb * NH + hh) * NDH + dv)) * NS + ss) = *(short4v*)pk;
      }
    }
  }
}

// ---------------- RoPE (in-place, interleaved pairs) ----------------
__global__ __launch_bounds__(256) void rope_kernel(u16* kr, u16* qr) {
  int tid = blockIdx.x * 256 + threadIdx.x;
  int which = tid >> 19;
  int loc = tid & ((1 << 19) - 1);
  int row = loc >> 7;
  int ch = loc & 127;
  int s = row & (NS - 1);
  u16* p = (which ? qr : kr) + (size_t)row * (NH * NDR) + ch * 8;
  short8 v = *(short8*)p;
  int jb = (ch & 7) * 4;
  u16 o[8];
#pragma unroll
  for (int q = 0; q < 4; ++q) {
    int j = jb + q;
    float invf = exp2f(-(float)j * 0.41524101186f);
    float ang = (float)s * invf;
    float sn = sinf(ang), cs = cosf(ang);
    float x1 = bf2f(((u16*)&v)[2 * q]);
    float x2 = bf2f(((u16*)&v)[2 * q + 1]);
    o[2 * q]     = f2bf(x1 * cs - x2 * sn);
    o[2 * q + 1] = f2bf(x1 * sn + x2 * cs);
  }
  *(short8*)p = *(short8*)o;
}

// ---------------- flash attention (swapped QK^T, in-register P) ----------------
// 4 waves x 32 q-rows. Double-buffered K/V (80KB dynamic LDS), unroll-2 so buffer
// offsets are compile-time; all swizzled LDS read addresses are loop-invariant
// VGPRs + ds offset immediates (krow&7 == cl&7, vrow&7 == cl&7).
__global__ __launch_bounds__(256, 2) void attn_kernel(
    const u16* __restrict__ Qc, const u16* __restrict__ Qr,
    const u16* __restrict__ Kc, const u16* __restrict__ Kr,
    const u16* __restrict__ VT, u16* __restrict__ Ctx) {
  extern __shared__ char smem[];   // 2 x (24576 K + 16384 V) = 81920
  const int t = threadIdx.x, w = t >> 6, l = t & 63;
  const int g = l >> 4, cl = l & 15;
  const int lin = blockIdx.x;
  const int xcd = lin & 7, idx = lin >> 3;
  const int bh = xcd * 4 + (idx >> 4);
  const int qb = idx & 15;
  const int b = bh >> 4, h = bh & 15;
  const int q0 = qb * 128 + w * 32;

  short8 qf[2][6];
#pragma unroll
  for (int qr = 0; qr < 2; ++qr) {
    const u16* qc = Qc + ((size_t)(b * NS + q0 + qr * 16 + cl)) * NHID + h * NDH + g * 8;
    const u16* qrp = Qr + ((size_t)(b * NS + q0 + qr * 16 + cl)) * (NH * NDR) + h * NDR + g * 8;
#pragma unroll
    for (int c = 0; c < 4; ++c) qf[qr][c] = *(const short8*)(qc + c * 32);
    qf[qr][4] = *(const short8*)(qrp);
    qf[qr][5] = *(const short8*)(qrp + 32);
  }
#pragma unroll
  for (int qr = 0; qr < 2; ++qr)
#pragma unroll
    for (int c = 0; c < 6; ++c) asm volatile("" :: "v"(qf[qr][c]));

  // staging pointers (inverse-swizzled global source, linear LDS dest)
  const u16* kptr[6]; int kstep[6];
#pragma unroll
  for (int r = 0; r < 6; ++r) {
    int Lb = r * 4096 + t * 16;
    int row = Lb / 384;
    int off = Lb - row * 384;
    int c = (off ^ ((row & 7) << 4)) >> 1;
    if (c < NDH) { kptr[r] = Kc + ((size_t)(b * NS + row)) * NHID + h * NDH + c; kstep[r] = 64 * NHID; }
    else { kptr[r] = Kr + ((size_t)(b * NS + row)) * (NH * NDR) + h * NDR + (c - NDH); kstep[r] = 64 * NH * NDR; }
  }
  const u16* vptr[4];
#pragma unroll
  for (int r = 0; r < 4; ++r) {
    int Lb = r * 4096 + t * 16;
    int row = Lb >> 7, off = Lb & 127;
    int c = (off ^ ((row & 7) << 4)) >> 1;
    vptr[r] = VT + ((size_t)(bh * NDH + row)) * NS + c;
  }

  // loop-invariant swizzled LDS read addresses
  const int xo = (cl & 7) << 4;
  int kaddr[6], vaddr[4];
#pragma unroll
  for (int c = 0; c < 6; ++c) kaddr[c] = cl * 384 + ((c * 64 + g * 16) ^ xo);
#pragma unroll
  for (int n = 0; n < 4; ++n) vaddr[n] = 24576 + cl * 128 + ((n * 32 + g * 8) ^ xo);

  float m2[2] = {-1e30f, -1e30f};
  float lsum[2] = {0.f, 0.f};
  const f32x4 vzero = {0.f, 0.f, 0.f, 0.f};
  f32x4 o[2][8];
#pragma unroll
  for (int qr = 0; qr < 2; ++qr)
#pragma unroll
    for (int d = 0; d < 8; ++d) o[qr][d] = vzero;
  const float scale2 = 0.10411757f;  // (1/sqrt(192)) * log2(e)

  auto stage_into = [&](int bufOff) {
#pragma unroll
    for (int r = 0; r < 6; ++r) { async16(kptr[r], smem + bufOff + r * 4096 + t * 16); kptr[r] += kstep[r]; }
#pragma unroll
    for (int r = 0; r < 4; ++r) { async16(vptr[r], smem + bufOff + 24576 + r * 4096 + t * 16); vptr[r] += 64; }
  };
  stage_into(0);

  auto tile = [&](auto bufc, bool stageNext) {
    constexpr int BO = decltype(bufc)::value;
    if (stageNext) {
      stage_into(BO ^ 40960);
      asm volatile("s_waitcnt vmcnt(10)" ::: "memory");
    } else {
      asm volatile("s_waitcnt vmcnt(0)" ::: "memory");
    }
    __builtin_amdgcn_s_barrier();
    asm volatile("" ::: "memory");

    // QK^T (swapped): lane holds P rows k=n*16+g*4+r, col q=cl
    f32x4 sa[2][4];
#pragma unroll
    for (int qr = 0; qr < 2; ++qr)
#pragma unroll
      for (int n = 0; n < 4; ++n) sa[qr][n] = vzero;
#pragma unroll
    for (int n = 0; n < 4; ++n) {
      short8 kf[6];
#pragma unroll
      for (int c = 0; c < 6; ++c)
        kf[c] = *(const short8*)(smem + kaddr[c] + (BO + n * 6144));
      __builtin_amdgcn_s_setprio(1);
#pragma unroll
      for (int c = 0; c < 6; ++c) {
        sa[0][n] = __builtin_amdgcn_mfma_f32_16x16x32_bf16(kf[c], qf[0][c], sa[0][n], 0, 0, 0);
        sa[1][n] = __builtin_amdgcn_mfma_f32_16x16x32_bf16(kf[c], qf[1][c], sa[1][n], 0, 0, 0);
      }
      __builtin_amdgcn_s_setprio(0);
    }

    // in-lane online softmax
    short4v pb[2][4];
#pragma unroll
    for (int qr = 0; qr < 2; ++qr) {
      float mx = fmaxf(fmaxf(sa[qr][0][0], sa[qr][0][1]), fmaxf(sa[qr][0][2], sa[qr][0][3]));
#pragma unroll
      for (int n = 1; n < 4; ++n)
        mx = fmaxf(mx, fmaxf(fmaxf(sa[qr][n][0], sa[qr][n][1]), fmaxf(sa[qr][n][2], sa[qr][n][3])));
      mx = fmaxf(mx, __shfl_xor(mx, 16));
      mx = fmaxf(mx, __shfl_xor(mx, 32));
      float mxs = mx * scale2;
      if (!__all(mxs <= m2[qr] + 6.0f)) {
        float mn = fmaxf(m2[qr], mxs);
        float sf = exp2f(m2[qr] - mn);
        m2[qr] = mn;
        lsum[qr] *= sf;
        f32x4 sfv = {sf, sf, sf, sf};
#pragma unroll
        for (int d = 0; d < 8; ++d) o[qr][d] *= sfv;
      }
      float nm = -m2[qr];
      float ps = 0.f;
#pragma unroll
      for (int n = 0; n < 4; ++n) {
        float p0 = exp2f(fmaf(sa[qr][n][0], scale2, nm));
        float p1 = exp2f(fmaf(sa[qr][n][1], scale2, nm));
        float p2 = exp2f(fmaf(sa[qr][n][2], scale2, nm));
        float p3 = exp2f(fmaf(sa[qr][n][3], scale2, nm));
        ps += (p0 + p1) + (p2 + p3);
        union { uint32_t u[2]; short4v s; } pu;
        pu.u[0] = cvtpk(p0, p1);
        pu.u[1] = cvtpk(p2, p3);
        pb[qr][n] = pu.s;
      }
      ps += __shfl_xor(ps, 16);
      ps += __shfl_xor(ps, 32);
      lsum[qr] += ps;
    }

    // PV: O^T[dv][q] += V^T-frag x P^T-frag (K=16 per n)
#pragma unroll
    for (int n = 0; n < 4; ++n) {
      __builtin_amdgcn_s_setprio(1);
#pragma unroll
      for (int d = 0; d < 8; ++d) {
        short4v va = *(const short4v*)(smem + vaddr[n] + (BO + d * 2048));
        o[0][d] = __builtin_amdgcn_mfma_f32_16x16x16bf16_1k(va, pb[0][n], o[0][d], 0, 0, 0);
        o[1][d] = __builtin_amdgcn_mfma_f32_16x16x16bf16_1k(va, pb[1][n], o[1][d], 0, 0, 0);
      }
      __builtin_amdgcn_s_setprio(0);
    }

    asm volatile("s_waitcnt lgkmcnt(0)" ::: "memory");
    __builtin_amdgcn_s_barrier();
  };

  for (int kv = 0; kv < NS / 64; kv += 2) {
    tile(IC<0>{}, true);
    tile(IC<40960>{}, kv + 2 < NS / 64);
  }

  // epilogue
#pragma unroll
  for (int qr = 0; qr < 2; ++qr) {
    float invq = 1.f / lsum[qr];
    u16* dst = Ctx + ((size_t)(b * NS + q0 + qr * 16 + cl)) * NHID + h * NDH + g * 4;
#pragma unroll
    for (int d = 0; d < 8; ++d) {
      float a0 = o[qr][d][0] * invq, a1 = o[qr][d][1] * invq;
      float a2 = o[qr][d][2] * invq, a3 = o[qr][d][3] * invq;
      union { uint32_t u[2]; short4v s; } pu;
      pu.u[0] = cvtpk(a0, a1);
      pu.u[1] = cvtpk(a2, a3);
      *(short4v*)(dst + d * 16) = pu.s;
    }
  }
}

// ---------------- host ----------------
extern "C" void kernel_launch(void* const* d_in, const int* in_sizes, int n_in,
                              void* d_out, int out_size, void* d_ws, size_t ws_size,
                              hipStream_t stream) {
  (void)in_sizes; (void)n_in; (void)out_size;
  const float* x      = (const float*)d_in[0];
  const float* d_kv_w = (const float*)d_in[1];
  const float* d_kv_b = (const float*)d_in[2];
  const float* u_k_w  = (const float*)d_in[3];
  const float* u_k_b  = (const float*)d_in[4];
  const float* u_v_w  = (const float*)d_in[5];
  const float* u_v_b  = (const float*)d_in[6];
  const float* d_q_w  = (const float*)d_in[7];
  const float* d_q_b  = (const float*)d_in[8];
  const float* u_q_w  = (const float*)d_in[9];
  const float* u_q_b  = (const float*)d_in[10];
  const float* qr_w   = (const float*)d_in[11];
  const float* qr_b   = (const float*)d_in[12];
  const float* out_w  = (const float*)d_in[13];
  const float* out_b  = (const float*)d_in[14];

  char* ws = (char*)d_ws;
  size_t off = 0;
  auto alloc = [&](size_t bytes) -> void* {
    void* p = ws + off;
    off += (bytes + 255) & ~(size_t)255;
    return p;
  };
  u16* xb   = (u16*)alloc((size_t)NB * NS * NHID * 2);
  u16* wdkv = (u16*)alloc((size_t)NC * NHID * 2);
  u16* wuk  = (u16*)alloc((size_t)NH * NDH * NC * 2);
  u16* wuv  = (u16*)alloc((size_t)NH * NDH * NC * 2);
  u16* wdq  = (u16*)alloc((size_t)NC * NHID * 2);
  u16* wuq  = (u16*)alloc((size_t)NH * NDH * NC * 2);
  u16* wqr  = (u16*)alloc((size_t)NH * NDR * NC * 2);
  u16* wout = (u16*)alloc((size_t)NHID * NH * NDH * 2);
  u16* kvc  = (u16*)alloc((size_t)NB * NS * NC * 2);
  u16* qlat = (u16*)alloc((size_t)NB * NS * NC * 2);
  u16* Kc   = (u16*)alloc((size_t)NB * NS * NH * NDH * 2);
  u16* Krt  = (u16*)alloc((size_t)NB * NS * NH * NDR * 2);
  u16* Qc   = (u16*)alloc((size_t)NB * NS * NH * NDH * 2);
  u16* Qrt  = (u16*)alloc((size_t)NB * NS * NH * NDR * 2);
  u16* VT   = (u16*)alloc((size_t)NB * NH * NDH * NS * 2);
  u16* ctx  = xb;  // alias: x (bf16) dead after latent GEMM
  if (off > ws_size) return;

  // 1) cast
  {
    CastArgs ca;
    const float* srcs[8] = {x, d_kv_w, u_k_w, u_v_w, d_q_w, u_q_w, qr_w, out_w};
    u16* dsts[8] = {xb, wdkv, wuk, wuv, wdq, wuq, wqr, wout};
    int sizes[8] = {NB * NS * NHID, NC * NHID, NH * NDH * NC, NH * NDH * NC,
                    NC * NHID, NH * NDH * NC, NH * NDR * NC, NHID * NH * NDH};
    int st = 0;
    for (int i = 0; i < 8; ++i) {
      ca.src[i] = srcs[i]; ca.dst[i] = dsts[i]; ca.start[i] = st;
      st += sizes[i] / 2048;
    }
    cast_kernel<<<dim3(st), dim3(256), 0, stream>>>(ca);
  }

  // 2) latent GEMM: kv_c and q_lat (K=2048, N=512 each)
  {
    GemmArgs ga;
    ga.nseg = 2;
    ga.seg[0] = {xb, wdkv, d_kv_b, kvc, NHID, 0, NC};
    ga.seg[1] = {xb, wdq,  d_q_b,  qlat, NHID, 0, NC};
    for (int i = 2; i < 5; ++i) ga.seg[i] = ga.seg[0];
    ga.nbstart[0] = 0; ga.nbstart[1] = 4; ga.nbstart[2] = 8;
    ga.nbstart[3] = 8; ga.nbstart[4] = 8; ga.nbstart[5] = 8;
    gemm_bt<<<dim3(8, 32), dim3(256), 0, stream>>>(ga);
  }

  // 3) up GEMMs: k_c, v(->V^T), k_r, q_c, q_r (K=512)
  {
    GemmArgs ga;
    ga.nseg = 5;
    ga.seg[0] = {kvc,  wuk, u_k_b, Kc,  NC, 0, NH * NDH};
    ga.seg[1] = {kvc,  wuv, u_v_b, VT,  NC, 1, 0};
    ga.seg[2] = {kvc,  wqr, qr_b,  Krt, NC, 0, NH * NDR};
    ga.seg[3] = {qlat, wuq, u_q_b, Qc,  NC, 0, NH * NDH};
    ga.seg[4] = {qlat, wqr, qr_b,  Qrt, NC, 0, NH * NDR};
    ga.nbstart[0] = 0;  ga.nbstart[1] = 16; ga.nbstart[2] = 32;
    ga.nbstart[3] = 40; ga.nbstart[4] = 56; ga.nbstart[5] = 64;
    gemm_bt<<<dim3(64, 32), dim3(256), 0, stream>>>(ga);
  }

  // 4) RoPE in-place
  rope_kernel<<<dim3(4096), dim3(256), 0, stream>>>(Krt, Qrt);

  // 5) attention (80KB dynamic LDS, 2 blocks/CU)
  hipFuncSetAttribute((const void*)attn_kernel,
                      hipFuncAttributeMaxDynamicSharedMemorySize, 81920);
  attn_kernel<<<dim3(512), dim3(256), 81920, stream>>>(Qc, Qrt, Kc, Krt, VT, ctx);

  // 6) out projection (f32 out + bias)
  {
    GemmArgs ga;
    ga.nseg = 1;
    ga.seg[0] = {ctx, wout, out_b, d_out, NHID, 2, NHID};
    for (int i = 1; i < 5; ++i) ga.seg[i] = ga.seg[0];
    ga.nbstart[0] = 0;
    for (int i = 1; i < 6; ++i) ga.nbstart[i] = 16;
    gemm_bt<<<dim3(16, 32), dim3(256), 0, stream>>>(ga);
  }
}

// Round 4
// 280.454 us; speedup vs baseline: 1.3808x; 1.0828x over previous
//
#include <hip/hip_runtime.h>
#include <hip/hip_bf16.h>
#include <math.h>
#include <stdint.h>

#define NB 2
#define NS 2048
#define NH 16
#define NDH 128
#define NDR 64
#define NHID 2048
#define NC 512

typedef unsigned short u16;
typedef short short8 __attribute__((ext_vector_type(8)));
typedef short short4v __attribute__((ext_vector_type(4)));
typedef float f32x4 __attribute__((ext_vector_type(4)));
typedef float f32x16 __attribute__((ext_vector_type(16)));
typedef int int2v __attribute__((ext_vector_type(2)));

template <int V> struct IC { static constexpr int value = V; };

__device__ __forceinline__ u16 f2bf(float f) {
  union { float f; uint32_t u; } c; c.f = f;
  uint32_t u = c.u + 0x7fffu + ((c.u >> 16) & 1u);
  return (u16)(u >> 16);
}
__device__ __forceinline__ float bf2f(u16 b) {
  union { uint32_t u; float f; } c; c.u = ((uint32_t)b) << 16;
  return c.f;
}
__device__ __forceinline__ void async16(const void* g, void* l) {
  __builtin_amdgcn_global_load_lds((const __attribute__((address_space(1))) void*)g,
                                   (__attribute__((address_space(3))) void*)l, 16, 0, 0);
}
__device__ __forceinline__ int cvtpk(float a, float b) {
  int r;
  asm("v_cvt_pk_bf16_f32 %0, %1, %2" : "=v"(r) : "v"(a), "v"(b));
  return r;
}

// ---------------- cast f32 -> bf16 ----------------
struct CastArgs {
  const float* src[8];
  u16* dst[8];
  int start[8];
};

__global__ __launch_bounds__(256) void cast_kernel(CastArgs a) {
  int blk = blockIdx.x;
  int ti = 0;
#pragma unroll
  for (int i = 1; i < 8; ++i) ti += (blk >= a.start[i]) ? 1 : 0;
  size_t off = (size_t)(blk - a.start[ti]) * 2048 + (size_t)threadIdx.x * 8;
  const float4* s = (const float4*)(a.src[ti] + off);
  float4 v0 = s[0], v1 = s[1];
  u16 o[8];
  o[0] = f2bf(v0.x); o[1] = f2bf(v0.y); o[2] = f2bf(v0.z); o[3] = f2bf(v0.w);
  o[4] = f2bf(v1.x); o[5] = f2bf(v1.y); o[6] = f2bf(v1.z); o[7] = f2bf(v1.w);
  *(short8*)(a.dst[ti] + off) = *(short8*)o;
}

// ---------------- generic B^T GEMM, 2-phase pipelined ----------------
struct GemmSeg {
  const u16* A;
  const u16* W;
  const float* bias;
  void* dst;
  int K;
  int mode;   // 0: bf16 rowmajor; 1: V^T pack -> [b][h][dv][s]; 2: f32 rowmajor
  int ldc;
};
struct GemmArgs {
  GemmSeg seg[5];
  int nbstart[6];
  int nseg;
};

__global__ __launch_bounds__(256) void gemm_bt(GemmArgs ga) {
  __shared__ char glds[32768];
  const int nb = blockIdx.x, mb = blockIdx.y;
  int si = 0;
  for (int i = 1; i < ga.nseg; ++i) si += (nb >= ga.nbstart[i]) ? 1 : 0;
  GemmSeg sg = ga.seg[si];
  const int nbl = nb - ga.nbstart[si];
  const int K = sg.K;
  const int t = threadIdx.x;
  const int l = t & 63, w = t >> 6;
  const int r0 = t >> 2, c0 = (t & 3) * 8;
  const int wm = (w >> 1) * 64, wn = (w & 1) * 64;
  const int frow = l & 15, fk = (l >> 4) * 8;
  const int lafO = ((wm + frow) * 32 + fk) * 2;
  const int lbfO = 8192 + ((wn + frow) * 32 + fk) * 2;

  const u16* apA = sg.A + (size_t)mb * 128 * K + (size_t)r0 * K + c0;
  const u16* wpA = sg.W + (size_t)nbl * 128 * K + (size_t)r0 * K + c0;

  auto stage = [&](int bufOff) {
    async16(apA, glds + bufOff + t * 16);
    async16(apA + (size_t)64 * K, glds + bufOff + 4096 + t * 16);
    async16(wpA, glds + bufOff + 8192 + t * 16);
    async16(wpA + (size_t)64 * K, glds + bufOff + 12288 + t * 16);
    apA += 32; wpA += 32;
  };

  const f32x4 vzero = {0.f, 0.f, 0.f, 0.f};
  f32x4 acc[4][4];
#pragma unroll
  for (int i = 0; i < 4; ++i)
#pragma unroll
    for (int j = 0; j < 4; ++j) acc[i][j] = vzero;

  stage(0);
  const int nk = K / 32;

  auto ktile = [&](auto bufc, bool stageNext) {
    constexpr int BO = decltype(bufc)::value;
    if (stageNext) {
      stage(BO ^ 16384);
      asm volatile("s_waitcnt vmcnt(4)" ::: "memory");
    } else {
      asm volatile("s_waitcnt vmcnt(0)" ::: "memory");
    }
    __builtin_amdgcn_s_barrier();
    asm volatile("" ::: "memory");
    short8 af[4], bfr[4];
#pragma unroll
    for (int i = 0; i < 4; ++i) af[i] = *(const short8*)(glds + BO + lafO + i * 1024);
#pragma unroll
    for (int j = 0; j < 4; ++j) bfr[j] = *(const short8*)(glds + BO + lbfO + j * 1024);
    __builtin_amdgcn_s_setprio(1);
#pragma unroll
    for (int i = 0; i < 4; ++i)
#pragma unroll
      for (int j = 0; j < 4; ++j)
        acc[i][j] = __builtin_amdgcn_mfma_f32_16x16x32_bf16(af[i], bfr[j], acc[i][j], 0, 0, 0);
    __builtin_amdgcn_s_setprio(0);
    asm volatile("s_waitcnt lgkmcnt(0)" ::: "memory");
    __builtin_amdgcn_s_barrier();
  };

  for (int kk = 0; kk < nk; kk += 2) {
    ktile(IC<0>{}, true);
    ktile(IC<16384>{}, kk + 2 < nk);
  }

  const int rb = (l >> 4) * 4;
  const int cl = l & 15;
  if (sg.mode == 0) {
    u16* D = (u16*)sg.dst;
#pragma unroll
    for (int i = 0; i < 4; ++i)
#pragma unroll
      for (int j = 0; j < 4; ++j) {
        int col = nbl * 128 + wn + j * 16 + cl;
        float bv = sg.bias[col];
#pragma unroll
        for (int r = 0; r < 4; ++r) {
          int row = mb * 128 + wm + i * 16 + rb + r;
          D[(size_t)row * sg.ldc + col] = f2bf(acc[i][j][r] + bv);
        }
      }
  } else if (sg.mode == 2) {
    float* D = (float*)sg.dst;
#pragma unroll
    for (int i = 0; i < 4; ++i)
#pragma unroll
      for (int j = 0; j < 4; ++j) {
        int col = nbl * 128 + wn + j * 16 + cl;
        float bv = sg.bias[col];
#pragma unroll
        for (int r = 0; r < 4; ++r) {
          int row = mb * 128 + wm + i * 16 + rb + r;
          D[(size_t)row * sg.ldc + col] = acc[i][j][r] + bv;
        }
      }
  } else {
    u16* D = (u16*)sg.dst;
#pragma unroll
    for (int i = 0; i < 4; ++i) {
      int row0 = mb * 128 + wm + i * 16 + rb;
      int bb = row0 >> 11, ss = row0 & (NS - 1);
#pragma unroll
      for (int j = 0; j < 4; ++j) {
        int col = nbl * 128 + wn + j * 16 + cl;
        int hh = col >> 7, dv = col & 127;
        float bv = sg.bias[col];
        u16 pk[4];
#pragma unroll
        for (int r = 0; r < 4; ++r) pk[r] = f2bf(acc[i][j][r] + bv);
        *(short4v*)(D + ((size_t)((bb * NH + hh) * NDH + dv)) * NS + ss) = *(short4v*)pk;
      }
    }
  }
}

// ---------------- RoPE (in-place, interleaved pairs) ----------------
__global__ __launch_bounds__(256) void rope_kernel(u16* kr, u16* qr) {
  int tid = blockIdx.x * 256 + threadIdx.x;
  int which = tid >> 19;
  int loc = tid & ((1 << 19) - 1);
  int row = loc >> 7;
  int ch = loc & 127;
  int s = row & (NS - 1);
  u16* p = (which ? qr : kr) + (size_t)row * (NH * NDR) + ch * 8;
  short8 v = *(short8*)p;
  int jb = (ch & 7) * 4;
  u16 o[8];
#pragma unroll
  for (int q = 0; q < 4; ++q) {
    int j = jb + q;
    float invf = exp2f(-(float)j * 0.41524101186f);
    float ang = (float)s * invf;
    float sn = sinf(ang), cs = cosf(ang);
    float x1 = bf2f(((u16*)&v)[2 * q]);
    float x2 = bf2f(((u16*)&v)[2 * q + 1]);
    o[2 * q]     = f2bf(x1 * cs - x2 * sn);
    o[2 * q + 1] = f2bf(x1 * sn + x2 * cs);
  }
  *(short8*)p = *(short8*)o;
}

// ---------------- flash attention: 32x32 MFMA everywhere ----------------
// 4 waves x 32 q-cols. S^T = mfma32(K, Q): lane q-col = l&31, 16 k-rows per
// n-block (k = 8*(r>>2) + 4*hi + (r&3), hi = l>>5). PV B-frag built in-register:
// per 16-k window, 4 cvtpk + 2 permlane32_swap (ret[0]=row0s, ret[1]=row1s).
__global__ __launch_bounds__(256, 2) void attn_kernel(
    const u16* __restrict__ Qc, const u16* __restrict__ Qr,
    const u16* __restrict__ Kc, const u16* __restrict__ Kr,
    const u16* __restrict__ VT, u16* __restrict__ Ctx) {
  extern __shared__ char smem[];   // 2 x (24576 K + 16384 V) = 81920
  const int t = threadIdx.x, w = t >> 6, l = t & 63;
  const int hi = l >> 5, q32 = l & 31;
  const int lin = blockIdx.x;
  const int xcd = lin & 7, idx = lin >> 3;
  const int bh = xcd * 4 + (idx >> 4);
  const int qb = idx & 15;
  const int b = bh >> 4, h = bh & 15;
  const int q0 = qb * 128 + w * 32;

  // Q B-frags: lane: q-col = q0+q32, d-span dw*16 + hi*8
  short8 qf[12];
  {
    const u16* qcp = Qc + ((size_t)(b * NS + q0 + q32)) * NHID + h * NDH + hi * 8;
    const u16* qrp = Qr + ((size_t)(b * NS + q0 + q32)) * (NH * NDR) + h * NDR + hi * 8;
#pragma unroll
    for (int dw = 0; dw < 8; ++dw) qf[dw] = *(const short8*)(qcp + dw * 16);
#pragma unroll
    for (int dw = 0; dw < 4; ++dw) qf[8 + dw] = *(const short8*)(qrp + dw * 16);
  }
#pragma unroll
  for (int dw = 0; dw < 12; ++dw) asm volatile("" :: "v"(qf[dw]));

  // staging pointers (inverse-swizzled global source, linear LDS dest)
  const u16* kptr[6]; int kstep[6];
#pragma unroll
  for (int r = 0; r < 6; ++r) {
    int Lb = r * 4096 + t * 16;
    int row = Lb / 384;
    int off = Lb - row * 384;
    int c = (off ^ ((row & 7) << 4)) >> 1;
    if (c < NDH) { kptr[r] = Kc + ((size_t)(b * NS + row)) * NHID + h * NDH + c; kstep[r] = 64 * NHID; }
    else { kptr[r] = Kr + ((size_t)(b * NS + row)) * (NH * NDR) + h * NDR + (c - NDH); kstep[r] = 64 * NH * NDR; }
  }
  const u16* vptr[4];
#pragma unroll
  for (int r = 0; r < 4; ++r) {
    int Lb = r * 4096 + t * 16;
    int row = Lb >> 7, off = Lb & 127;
    int c = (off ^ ((row & 7) << 4)) >> 1;
    vptr[r] = VT + ((size_t)(bh * NDH + row)) * NS + c;
  }

  const int kswz = (l & 7) << 4;
  float m2 = -1e30f, lsum = 0.f;
  f32x16 acc[4];
#pragma unroll
  for (int i = 0; i < 4; ++i)
#pragma unroll
    for (int r = 0; r < 16; ++r) acc[i][r] = 0.f;
  const float scale2 = 0.10411757f;  // (1/sqrt(192)) * log2(e)

  auto stage_into = [&](int bufOff) {
#pragma unroll
    for (int r = 0; r < 6; ++r) { async16(kptr[r], smem + bufOff + r * 4096 + t * 16); kptr[r] += kstep[r]; }
#pragma unroll
    for (int r = 0; r < 4; ++r) { async16(vptr[r], smem + bufOff + 24576 + r * 4096 + t * 16); vptr[r] += 64; }
  };
  stage_into(0);

  auto tile = [&](auto bufc, bool stageNext) {
    constexpr int BO = decltype(bufc)::value;
    if (stageNext) {
      stage_into(BO ^ 40960);
      asm volatile("s_waitcnt vmcnt(10)" ::: "memory");
    } else {
      asm volatile("s_waitcnt vmcnt(0)" ::: "memory");
    }
    __builtin_amdgcn_s_barrier();
    asm volatile("" ::: "memory");

    // QK^T: sa[n] = S^T 32x32 (keys n*32..n*32+31 x q-cols)
    f32x16 sa[2];
#pragma unroll
    for (int n = 0; n < 2; ++n)
#pragma unroll
      for (int r = 0; r < 16; ++r) sa[n][r] = 0.f;
#pragma unroll
    for (int dw = 0; dw < 12; ++dw) {
      int ko = q32 * 384 + ((dw * 32 + hi * 16) ^ kswz);
      short8 k0 = *(const short8*)(smem + BO + ko);
      short8 k1 = *(const short8*)(smem + BO + 12288 + ko);
      __builtin_amdgcn_s_setprio(1);
      sa[0] = __builtin_amdgcn_mfma_f32_32x32x16_bf16(k0, qf[dw], sa[0], 0, 0, 0);
      sa[1] = __builtin_amdgcn_mfma_f32_32x32x16_bf16(k1, qf[dw], sa[1], 0, 0, 0);
      __builtin_amdgcn_s_setprio(0);
    }

    // online softmax (one q-col per lane; halves combined via shfl_xor 32)
    float mx = sa[0][0];
#pragma unroll
    for (int r = 1; r < 16; ++r) mx = fmaxf(mx, sa[0][r]);
#pragma unroll
    for (int r = 0; r < 16; ++r) mx = fmaxf(mx, sa[1][r]);
    mx = fmaxf(mx, __shfl_xor(mx, 32));
    float mxs = mx * scale2;
    if (!__all(mxs <= m2 + 6.0f)) {       // defer-max (T13)
      float mn = fmaxf(m2, mxs);
      float sf = exp2f(m2 - mn);
      m2 = mn;
      lsum *= sf;
#pragma unroll
      for (int i = 0; i < 4; ++i) acc[i] *= sf;
    }
    float nm = -m2;
    float ps = 0.f;
#pragma unroll
    for (int n = 0; n < 2; ++n)
#pragma unroll
      for (int r = 0; r < 16; ++r) {
        float p = exp2f(fmaf(sa[n][r], scale2, nm));
        sa[n][r] = p;
        ps += p;
      }
    ps += __shfl_xor(ps, 32);
    lsum += ps;

    // PV: per 16-k window W = n*2+w2: build B-frag via cvtpk+permlane32_swap
#pragma unroll
    for (int n = 0; n < 2; ++n) {
#pragma unroll
      for (int w2 = 0; w2 < 2; ++w2) {
        const int base = w2 * 8;
        int A0 = cvtpk(sa[n][base + 0], sa[n][base + 1]);
        int A1 = cvtpk(sa[n][base + 2], sa[n][base + 3]);
        int B0 = cvtpk(sa[n][base + 4], sa[n][base + 5]);
        int B1 = cvtpk(sa[n][base + 6], sa[n][base + 7]);
        int2v r02 = __builtin_amdgcn_permlane32_swap(A0, B0, false, false);
        int2v r13 = __builtin_amdgcn_permlane32_swap(A1, B1, false, false);
        union { int i[4]; short8 s; } F;
        F.i[0] = r02[0]; F.i[1] = r13[0]; F.i[2] = r02[1]; F.i[3] = r13[1];
        const int W = n * 2 + w2;
        const int vo = q32 * 128 + ((W * 32 + hi * 16) ^ kswz);
        __builtin_amdgcn_s_setprio(1);
#pragma unroll
        for (int d32 = 0; d32 < 4; ++d32) {
          short8 va = *(const short8*)(smem + BO + 24576 + d32 * 4096 + vo);
          acc[d32] = __builtin_amdgcn_mfma_f32_32x32x16_bf16(va, F.s, acc[d32], 0, 0, 0);
        }
        __builtin_amdgcn_s_setprio(0);
      }
    }

    asm volatile("s_waitcnt lgkmcnt(0)" ::: "memory");
    __builtin_amdgcn_s_barrier();
  };

  for (int kv = 0; kv < NS / 64; kv += 2) {
    tile(IC<0>{}, true);
    tile(IC<40960>{}, kv + 2 < NS / 64);
  }

  // epilogue: dv = d32*32 + m2x*8 + hi*4 + j, q = q0 + q32
  float invq = 1.f / lsum;
  u16* dst = Ctx + ((size_t)(b * NS + q0 + q32)) * NHID + h * NDH + hi * 4;
#pragma unroll
  for (int d32 = 0; d32 < 4; ++d32)
#pragma unroll
    for (int m2x = 0; m2x < 4; ++m2x) {
      float a0 = acc[d32][m2x * 4 + 0] * invq, a1 = acc[d32][m2x * 4 + 1] * invq;
      float a2 = acc[d32][m2x * 4 + 2] * invq, a3 = acc[d32][m2x * 4 + 3] * invq;
      union { int i[2]; short4v s; } pu;
      pu.i[0] = cvtpk(a0, a1);
      pu.i[1] = cvtpk(a2, a3);
      *(short4v*)(dst + d32 * 32 + m2x * 8) = pu.s;
    }
}

// ---------------- host ----------------
extern "C" void kernel_launch(void* const* d_in, const int* in_sizes, int n_in,
                              void* d_out, int out_size, void* d_ws, size_t ws_size,
                              hipStream_t stream) {
  (void)in_sizes; (void)n_in; (void)out_size;
  const float* x      = (const float*)d_in[0];
  const float* d_kv_w = (const float*)d_in[1];
  const float* d_kv_b = (const float*)d_in[2];
  const float* u_k_w  = (const float*)d_in[3];
  const float* u_k_b  = (const float*)d_in[4];
  const float* u_v_w  = (const float*)d_in[5];
  const float* u_v_b  = (const float*)d_in[6];
  const float* d_q_w  = (const float*)d_in[7];
  const float* d_q_b  = (const float*)d_in[8];
  const float* u_q_w  = (const float*)d_in[9];
  const float* u_q_b  = (const float*)d_in[10];
  const float* qr_w   = (const float*)d_in[11];
  const float* qr_b   = (const float*)d_in[12];
  const float* out_w  = (const float*)d_in[13];
  const float* out_b  = (const float*)d_in[14];

  char* ws = (char*)d_ws;
  size_t off = 0;
  auto alloc = [&](size_t bytes) -> void* {
    void* p = ws + off;
    off += (bytes + 255) & ~(size_t)255;
    return p;
  };
  u16* xb   = (u16*)alloc((size_t)NB * NS * NHID * 2);
  u16* wdkv = (u16*)alloc((size_t)NC * NHID * 2);
  u16* wuk  = (u16*)alloc((size_t)NH * NDH * NC * 2);
  u16* wuv  = (u16*)alloc((size_t)NH * NDH * NC * 2);
  u16* wdq  = (u16*)alloc((size_t)NC * NHID * 2);
  u16* wuq  = (u16*)alloc((size_t)NH * NDH * NC * 2);
  u16* wqr  = (u16*)alloc((size_t)NH * NDR * NC * 2);
  u16* wout = (u16*)alloc((size_t)NHID * NH * NDH * 2);
  u16* kvc  = (u16*)alloc((size_t)NB * NS * NC * 2);
  u16* qlat = (u16*)alloc((size_t)NB * NS * NC * 2);
  u16* Kc   = (u16*)alloc((size_t)NB * NS * NH * NDH * 2);
  u16* Krt  = (u16*)alloc((size_t)NB * NS * NH * NDR * 2);
  u16* Qc   = (u16*)alloc((size_t)NB * NS * NH * NDH * 2);
  u16* Qrt  = (u16*)alloc((size_t)NB * NS * NH * NDR * 2);
  u16* VT   = (u16*)alloc((size_t)NB * NH * NDH * NS * 2);
  u16* ctx  = xb;  // alias: x (bf16) dead after latent GEMM
  if (off > ws_size) return;

  // 1) cast
  {
    CastArgs ca;
    const float* srcs[8] = {x, d_kv_w, u_k_w, u_v_w, d_q_w, u_q_w, qr_w, out_w};
    u16* dsts[8] = {xb, wdkv, wuk, wuv, wdq, wuq, wqr, wout};
    int sizes[8] = {NB * NS * NHID, NC * NHID, NH * NDH * NC, NH * NDH * NC,
                    NC * NHID, NH * NDH * NC, NH * NDR * NC, NHID * NH * NDH};
    int st = 0;
    for (int i = 0; i < 8; ++i) {
      ca.src[i] = srcs[i]; ca.dst[i] = dsts[i]; ca.start[i] = st;
      st += sizes[i] / 2048;
    }
    cast_kernel<<<dim3(st), dim3(256), 0, stream>>>(ca);
  }

  // 2) latent GEMM: kv_c and q_lat (K=2048, N=512 each)
  {
    GemmArgs ga;
    ga.nseg = 2;
    ga.seg[0] = {xb, wdkv, d_kv_b, kvc, NHID, 0, NC};
    ga.seg[1] = {xb, wdq,  d_q_b,  qlat, NHID, 0, NC};
    for (int i = 2; i < 5; ++i) ga.seg[i] = ga.seg[0];
    ga.nbstart[0] = 0; ga.nbstart[1] = 4; ga.nbstart[2] = 8;
    ga.nbstart[3] = 8; ga.nbstart[4] = 8; ga.nbstart[5] = 8;
    gemm_bt<<<dim3(8, 32), dim3(256), 0, stream>>>(ga);
  }

  // 3) up GEMMs: k_c, v(->V^T), k_r, q_c, q_r (K=512)
  {
    GemmArgs ga;
    ga.nseg = 5;
    ga.seg[0] = {kvc,  wuk, u_k_b, Kc,  NC, 0, NH * NDH};
    ga.seg[1] = {kvc,  wuv, u_v_b, VT,  NC, 1, 0};
    ga.seg[2] = {kvc,  wqr, qr_b,  Krt, NC, 0, NH * NDR};
    ga.seg[3] = {qlat, wuq, u_q_b, Qc,  NC, 0, NH * NDH};
    ga.seg[4] = {qlat, wqr, qr_b,  Qrt, NC, 0, NH * NDR};
    ga.nbstart[0] = 0;  ga.nbstart[1] = 16; ga.nbstart[2] = 32;
    ga.nbstart[3] = 40; ga.nbstart[4] = 56; ga.nbstart[5] = 64;
    gemm_bt<<<dim3(64, 32), dim3(256), 0, stream>>>(ga);
  }

  // 4) RoPE in-place
  rope_kernel<<<dim3(4096), dim3(256), 0, stream>>>(Krt, Qrt);

  // 5) attention (80KB dynamic LDS, 2 blocks/CU)
  hipFuncSetAttribute((const void*)attn_kernel,
                      hipFuncAttributeMaxDynamicSharedMemorySize, 81920);
  attn_kernel<<<dim3(512), dim3(256), 81920, stream>>>(Qc, Qrt, Kc, Krt, VT, ctx);

  // 6) out projection (f32 out + bias)
  {
    GemmArgs ga;
    ga.nseg = 1;
    ga.seg[0] = {ctx, wout, out_b, d_out, NHID, 2, NHID};
    for (int i = 1; i < 5; ++i) ga.seg[i] = ga.seg[0];
    ga.nbstart[0] = 0;
    for (int i = 1; i < 6; ++i) ga.nbstart[i] = 16;
    gemm_bt<<<dim3(16, 32), dim3(256), 0, stream>>>(ga);
  }
}